// Round 2
// baseline (1240.917 us; speedup 1.0000x reference)
//
#include <hip/hip_runtime.h>
#include <hip/hip_bf16.h>

#define HID 512
#define ENCD 512
#define NB 256
#define SEQ 1024
#define M_TOTAL (NB * SEQ)  // 262144

typedef short bf16x8 __attribute__((ext_vector_type(8)));
typedef float floatx4 __attribute__((ext_vector_type(4)));

__device__ __forceinline__ unsigned short f2bf(float f) {
    unsigned u = __builtin_bit_cast(unsigned, f);
    u += 0x7FFFu + ((u >> 16) & 1u);   // round-to-nearest-even
    return (unsigned short)(u >> 16);
}

__device__ __forceinline__ bf16x8 pack8(float4 a, float4 b) {
    bf16x8 r;
    r[0] = (short)f2bf(a.x); r[1] = (short)f2bf(a.y);
    r[2] = (short)f2bf(a.z); r[3] = (short)f2bf(a.w);
    r[4] = (short)f2bf(b.x); r[5] = (short)f2bf(b.y);
    r[6] = (short)f2bf(b.z); r[7] = (short)f2bf(b.w);
    return r;
}

// ---------------------------------------------------------------------------
// Kernel 1: proj_h = dh @ W_h^T (fp32), W_s -> bf16 conversion
// grid 128 blocks x 256 threads; block owns 2 batch rows (W_h reused x2)
// ---------------------------------------------------------------------------
__global__ __launch_bounds__(256) void prep_kernel(
    const float* __restrict__ dh,      // [256][512]
    const float* __restrict__ W_h,     // [512][512] (h, e)
    const float* __restrict__ W_s,     // [512][512] (h, e)
    float* __restrict__ proj_h,        // [256][512]
    unsigned short* __restrict__ Ws_bf)// [512][512] bf16
{
    __shared__ float sdh[2][HID];
    const int blk = blockIdx.x;
    const int t = threadIdx.x;
    const int b0 = blk * 2;

    // stage 2 dh rows: 256 float4 = 1024 floats
    {
        float4 d = ((const float4*)(dh + (size_t)b0 * HID))[t];
        ((float4*)&sdh[0][0])[t] = d;
    }

    // W_s bf16 conversion: 65536 float4 / (128*256) = 2 per thread
    #pragma unroll
    for (int i = 0; i < 2; ++i) {
        int f4 = (blk * 256 + t) * 2 + i;
        float4 w = ((const float4*)W_s)[f4];
        ushort4 o;
        o.x = f2bf(w.x); o.y = f2bf(w.y); o.z = f2bf(w.z); o.w = f2bf(w.w);
        ((ushort4*)Ws_bf)[f4] = o;
    }
    __syncthreads();

    #pragma unroll
    for (int i = 0; i < 2; ++i) {
        const int h = t + i * 256;
        const float4* wr = (const float4*)(W_h + (size_t)h * HID);
        float acc0 = 0.f, acc1 = 0.f;
        #pragma unroll 8
        for (int e4 = 0; e4 < HID / 4; ++e4) {
            float4 w  = wr[e4];
            float4 s0 = ((const float4*)&sdh[0][0])[e4];
            float4 s1 = ((const float4*)&sdh[1][0])[e4];
            acc0 += w.x * s0.x + w.y * s0.y + w.z * s0.z + w.w * s0.w;
            acc1 += w.x * s1.x + w.y * s1.y + w.z * s1.z + w.w * s1.w;
        }
        proj_h[(size_t)b0 * HID + h]       = acc0;
        proj_h[(size_t)(b0 + 1) * HID + h] = acc1;
    }
}

// ---------------------------------------------------------------------------
// Kernel 2: fused score GEMM, barrier-free, direct global->reg fragments.
// Block: 128 M x 512 N, 512 threads (8 waves), wave tile 64x128, BK=32.
// A (enc fp32) double-buffered one K-step ahead, converted in-reg to bf16.
// B (Ws bf16, 512KB, L2-resident) loaded per iter. L1 filters the intra-
// block fragment redundancy (per-iter A slab 16KB, B slab 32KB).
// ---------------------------------------------------------------------------
__global__ __launch_bounds__(512, 2) void score_gemm(
    const float* __restrict__ enc,          // [262144][512] fp32
    const unsigned short* __restrict__ Ws,  // [512][512] bf16 (h, e)
    const float* __restrict__ proj_h,       // [256][512]
    const float* __restrict__ v,            // [512]
    float* __restrict__ scores)             // [256][1024]
{
    __shared__ float sred[4][128];

    const int t    = threadIdx.x;
    const int wave = t >> 6;
    const int lane = t & 63;
    const int ln15 = lane & 15;
    const int lk   = lane >> 4;          // 0..3, k-chunk selector
    const int m0   = blockIdx.x * 128;   // single batch per block (1024%128==0)
    const int bb   = m0 >> 10;
    const int wm   = (wave & 1) * 64;    // wave M offset
    const int wn   = (wave >> 1) * 128;  // wave N offset

    floatx4 acc[4][8] = {};

    // per-lane A row pointers: row = m0+wm+mi*16+ln15, col base lk*8
    const float* ap[4];
    #pragma unroll
    for (int mi = 0; mi < 4; ++mi)
        ap[mi] = enc + (size_t)(m0 + wm + mi * 16 + ln15) * ENCD + lk * 8;

    // B fragment base: row (wn + nj*16 + ln15), col lk*8
    const unsigned short* bp = Ws + (size_t)(wn + ln15) * HID + lk * 8;

    // preload A for kt=0
    float4 a0[4], a1[4];
    #pragma unroll
    for (int mi = 0; mi < 4; ++mi) {
        a0[mi] = *(const float4*)(ap[mi]);
        a1[mi] = *(const float4*)(ap[mi] + 4);
    }

    #pragma unroll 2
    for (int kt = 0; kt < 16; ++kt) {
        const int k0 = kt * 32;

        // B fragments for this K-slab (L2/L1-hot)
        bf16x8 bfrag[8];
        #pragma unroll
        for (int nj = 0; nj < 8; ++nj)
            bfrag[nj] = *(const bf16x8*)(bp + (size_t)nj * 16 * HID + k0);

        // convert current A (loads issued a full iteration ago)
        bf16x8 afrag[4];
        #pragma unroll
        for (int mi = 0; mi < 4; ++mi)
            afrag[mi] = pack8(a0[mi], a1[mi]);

        // prefetch next A (HBM ~900cyc, hidden behind this iter's MFMAs)
        if (kt < 15) {
            #pragma unroll
            for (int mi = 0; mi < 4; ++mi) {
                a0[mi] = *(const float4*)(ap[mi] + k0 + 32);
                a1[mi] = *(const float4*)(ap[mi] + k0 + 36);
            }
        }

        #pragma unroll
        for (int mi = 0; mi < 4; ++mi)
            #pragma unroll
            for (int nj = 0; nj < 8; ++nj)
                acc[mi][nj] = __builtin_amdgcn_mfma_f32_16x16x32_bf16(
                    afrag[mi], bfrag[nj], acc[mi][nj], 0, 0, 0);
    }

    // Epilogue: tanh + v-dot, reduce over N.
    // C layout: col = lane&15, row = (lane>>4)*4 + reg
    float phv[8], vv[8];
    #pragma unroll
    for (int nj = 0; nj < 8; ++nj) {
        const int n = wn + nj * 16 + ln15;
        phv[nj] = proj_h[bb * HID + n];
        vv[nj]  = v[n];
    }

    #pragma unroll
    for (int mi = 0; mi < 4; ++mi) {
        #pragma unroll
        for (int r = 0; r < 4; ++r) {
            float s = 0.f;
            #pragma unroll
            for (int nj = 0; nj < 8; ++nj) {
                float x = acc[mi][nj][r] + phv[nj];
                float e = __expf(2.f * x);
                float th = 1.f - 2.f / (e + 1.f);  // tanh, saturates safely
                s += vv[nj] * th;
            }
            s += __shfl_xor(s, 8, 64);
            s += __shfl_xor(s, 4, 64);
            s += __shfl_xor(s, 2, 64);
            s += __shfl_xor(s, 1, 64);
            if (ln15 == 0) {
                const int row = wm + mi * 16 + lk * 4 + r;
                sred[wave >> 1][row] = s;
            }
        }
    }
    __syncthreads();
    if (t < 128)
        scores[m0 + t] = sred[0][t] + sred[1][t] + sred[2][t] + sred[3][t];
}

// ---------------------------------------------------------------------------
// Kernel 3: softmax over L, then context = alpha^T enc. One block per batch.
// 1024 threads: tx = t&127 owns a float4 column group, ty = t>>7 strides rows
// -> 8 independent float4 loads in flight per thread (HBM latency cover).
// ---------------------------------------------------------------------------
__global__ __launch_bounds__(1024) void softmax_ctx(
    const float* __restrict__ scores,  // [256][1024]
    const float* __restrict__ enc,     // [256][1024][512]
    float* __restrict__ ctx_out,       // [256][512]
    float* __restrict__ alpha_out)     // [256][1024]
{
    __shared__ float salpha[SEQ];
    __shared__ float sctx[8][ENCD];
    __shared__ float sbufA[16], sbufB[16];
    const int b = blockIdx.x;
    const int t = threadIdx.x;
    const int w = t >> 6;

    float sc = scores[(size_t)b * SEQ + t];

    float mx = sc;
    #pragma unroll
    for (int m = 32; m >= 1; m >>= 1) mx = fmaxf(mx, __shfl_xor(mx, m, 64));
    if ((t & 63) == 0) sbufA[w] = mx;
    __syncthreads();
    float gm = sbufA[0];
    #pragma unroll
    for (int i = 1; i < 16; ++i) gm = fmaxf(gm, sbufA[i]);

    float e0 = __expf(sc - gm);
    float ssum = e0;
    #pragma unroll
    for (int m = 32; m >= 1; m >>= 1) ssum += __shfl_xor(ssum, m, 64);
    if ((t & 63) == 0) sbufB[w] = ssum;
    __syncthreads();
    float tot = 0.f;
    #pragma unroll
    for (int i = 0; i < 16; ++i) tot += sbufB[i];
    const float inv = 1.f / tot;

    const float a0 = e0 * inv;
    salpha[t] = a0;
    alpha_out[(size_t)b * SEQ + t] = a0;
    __syncthreads();

    // context: tx owns columns [tx*4, tx*4+4), ty strides rows by 8
    const int tx = t & 127;
    const int ty = t >> 7;
    float4 acc = make_float4(0.f, 0.f, 0.f, 0.f);
    const float* ep = enc + (size_t)b * SEQ * ENCD + (size_t)tx * 4;
    #pragma unroll 8
    for (int l = ty; l < SEQ; l += 8) {
        float4 vv = *(const float4*)(ep + (size_t)l * ENCD);
        float a = salpha[l];
        acc.x += a * vv.x; acc.y += a * vv.y;
        acc.z += a * vv.z; acc.w += a * vv.w;
    }
    *(float4*)(&sctx[ty][tx * 4]) = acc;
    __syncthreads();

    if (t < ENCD) {
        float s = 0.f;
        #pragma unroll
        for (int y = 0; y < 8; ++y) s += sctx[y][t];
        ctx_out[(size_t)b * ENCD + t] = s;
    }
}

// ---------------------------------------------------------------------------
extern "C" void kernel_launch(void* const* d_in, const int* in_sizes, int n_in,
                              void* d_out, int out_size, void* d_ws, size_t ws_size,
                              hipStream_t stream) {
    const float* dh  = (const float*)d_in[0];  // decoder_hidden [256][512]
    const float* enc = (const float*)d_in[1];  // encoder_outputs [256][1024][512]
    const float* W_h = (const float*)d_in[2];  // [512][512]
    const float* W_s = (const float*)d_in[3];  // [512][512]
    const float* v   = (const float*)d_in[4];  // [1][512]

    float* ws = (float*)d_ws;
    float* proj_h = ws;                                // 131072 floats
    float* scores = ws + 131072;                       // 262144 floats
    unsigned short* Ws_bf = (unsigned short*)(ws + 131072 + 262144); // 262144 bf16

    float* ctx   = (float*)d_out;              // [256][512]
    float* alpha = (float*)d_out + NB * HID;   // [256][1024]

    prep_kernel<<<128, 256, 0, stream>>>(dh, W_h, W_s, proj_h, Ws_bf);
    score_gemm<<<M_TOTAL / 128, 512, 0, stream>>>(enc, Ws_bf, proj_h, v, scores);
    softmax_ctx<<<NB, 1024, 0, stream>>>(scores, enc, ctx, alpha);
}

// Round 4
// 1013.564 us; speedup vs baseline: 1.2243x; 1.2243x over previous
//
#include <hip/hip_runtime.h>
#include <hip/hip_bf16.h>

#define HID 512
#define ENCD 512
#define NB 256
#define SEQ 1024
#define M_TOTAL (NB * SEQ)  // 262144

typedef short bf16x8 __attribute__((ext_vector_type(8)));
typedef float floatx4 __attribute__((ext_vector_type(4)));

__device__ __forceinline__ unsigned short f2bf(float f) {
    unsigned u = __builtin_bit_cast(unsigned, f);
    u += 0x7FFFu + ((u >> 16) & 1u);   // round-to-nearest-even
    return (unsigned short)(u >> 16);
}
__device__ __forceinline__ ushort4 cvt4(float4 a) {
    return make_ushort4(f2bf(a.x), f2bf(a.y), f2bf(a.z), f2bf(a.w));
}

// ---------------------------------------------------------------------------
// Kernel 1: B-shuffle (W_s -> fragment-major bf16) + proj_h = dh @ W_h^T
// grid 128 x 256.
// Bshuf chunk id = ((wnG*16 + kt)*8 + nj)*64 + lane, 8 bf16 per chunk:
//   holds W_s[wnG*128 + nj*16 + (lane&15)][kt*32 + (lane>>4)*8 .. +8]
// so a wave's B-fragment load in the GEMM is one contiguous 1KB read.
// ---------------------------------------------------------------------------
__global__ __launch_bounds__(256) void prep_kernel(
    const float* __restrict__ dh,      // [256][512]
    const float* __restrict__ W_h,     // [512][512]
    const float* __restrict__ W_s,     // [512][512]
    float* __restrict__ proj_h,        // [256][512]
    unsigned short* __restrict__ Bshuf)// [32768][8] bf16
{
    __shared__ float sdh[2][HID];
    const int blk = blockIdx.x;
    const int t = threadIdx.x;
    const int b0 = blk * 2;

    // stage 2 dh rows (1024 floats = 256 float4)
    ((float4*)&sdh[0][0])[t] = ((const float4*)(dh + (size_t)b0 * HID))[t];

    // B shuffle: one 16B chunk per thread
    {
        const int id   = blk * 256 + t;
        const int lane = id & 63;
        const int nj   = (id >> 6) & 7;
        const int kt   = (id >> 9) & 15;
        const int wnG  = id >> 13;
        const int n = wnG * 128 + nj * 16 + (lane & 15);
        const int k = kt * 32 + (lane >> 4) * 8;
        const float* src = W_s + (size_t)n * HID + k;
        float4 s0 = *(const float4*)src;
        float4 s1 = *(const float4*)(src + 4);
        *(ushort4*)(Bshuf + (size_t)id * 8)     = cvt4(s0);
        *(ushort4*)(Bshuf + (size_t)id * 8 + 4) = cvt4(s1);
    }
    __syncthreads();

    #pragma unroll
    for (int i = 0; i < 2; ++i) {
        const int h = t + i * 256;
        const float4* wr = (const float4*)(W_h + (size_t)h * HID);
        float acc0 = 0.f, acc1 = 0.f;
        #pragma unroll 8
        for (int e4 = 0; e4 < HID / 4; ++e4) {
            float4 w  = wr[e4];
            float4 s0 = ((const float4*)&sdh[0][0])[e4];
            float4 s1 = ((const float4*)&sdh[1][0])[e4];
            acc0 += w.x * s0.x + w.y * s0.y + w.z * s0.z + w.w * s0.w;
            acc1 += w.x * s1.x + w.y * s1.y + w.z * s1.z + w.w * s1.w;
        }
        proj_h[(size_t)b0 * HID + h]       = acc0;
        proj_h[(size_t)(b0 + 1) * HID + h] = acc1;
    }
}

// ---------------------------------------------------------------------------
// Kernel 2: fused score GEMM. Block 128M x 512N, 512 threads, wave 64x128.
// A: coalesced global float4 -> bf16 cvt -> LDS (stride 40, dbuf,
//    single barrier/iter). Fragment read = one conflict-free ds_read_b128.
// B: fragment-major Bshuf, contiguous 1KB wave loads, registers only.
// ---------------------------------------------------------------------------
__global__ __launch_bounds__(512, 2) void score_gemm(
    const float* __restrict__ enc,           // [262144][512] fp32
    const unsigned short* __restrict__ Bshuf,// fragment-major bf16
    const float* __restrict__ proj_h,        // [256][512]
    const float* __restrict__ v,             // [512]
    float* __restrict__ scores)              // [256][1024]
{
    __shared__ unsigned short sA[2][128 * 40];
    __shared__ float sred[4][128];

    const int t    = threadIdx.x;
    const int wave = t >> 6;
    const int lane = t & 63;
    const int ln15 = lane & 15;
    const int lk   = lane >> 4;
    const int m0   = blockIdx.x * 128;   // 1024 % 128 == 0 -> single batch
    const int bb   = m0 >> 10;
    const int wm   = (wave & 1) * 64;
    const int wnG  = wave >> 1;
    const int wn   = wnG * 128;

    floatx4 acc[4][8] = {};

    // A staging coords: thread owns rows r0 and r0+64, col chunk c4 (4 floats)
    const int r0 = t >> 3, c4 = t & 7;
    const float* gA0 = enc + (size_t)(m0 + r0) * ENCD + c4 * 4;
    const float* gA1 = gA0 + (size_t)64 * ENCD;
    unsigned short* wp0 = &sA[0][r0 * 40 + c4 * 4];
    unsigned short* wp1 = &sA[0][(r0 + 64) * 40 + c4 * 4];
    const int bufStride = 128 * 40;

    // B fragment base: per (kt,nj) step is 512 ushorts (1KB)
    const unsigned short* bbase = Bshuf + ((size_t)wnG * 8192 + lane) * 8;

    // preload + stage iter 0
    {
        float4 p0 = *(const float4*)gA0;
        float4 p1 = *(const float4*)gA1;
        *(ushort4*)wp0 = cvt4(p0);
        *(ushort4*)wp1 = cvt4(p1);
    }
    __syncthreads();

    for (int kt = 0; kt < 16; ++kt) {
        const int cur = kt & 1;

        // prefetch next A (covered by this iter's MFMAs)
        float4 n0, n1;
        if (kt < 15) {
            n0 = *(const float4*)(gA0 + (kt + 1) * 32);
            n1 = *(const float4*)(gA1 + (kt + 1) * 32);
        }

        // B fragments: 8 contiguous 1KB wave loads (L1/L2-hot)
        bf16x8 bfrag[8];
        #pragma unroll
        for (int nj = 0; nj < 8; ++nj)
            bfrag[nj] = *(const bf16x8*)(bbase + ((size_t)(kt * 8 + nj)) * 512);

        // A fragments: one ds_read_b128 each, bank-tiling conflict-free
        bf16x8 afrag[4];
        #pragma unroll
        for (int mi = 0; mi < 4; ++mi)
            afrag[mi] = *(const bf16x8*)(&sA[cur][(wm + mi * 16 + ln15) * 40 + lk * 8]);

        #pragma unroll
        for (int mi = 0; mi < 4; ++mi)
            #pragma unroll
            for (int nj = 0; nj < 8; ++nj)
                acc[mi][nj] = __builtin_amdgcn_mfma_f32_16x16x32_bf16(
                    afrag[mi], bfrag[nj], acc[mi][nj], 0, 0, 0);

        // stage next buffer (write-before-barrier; read next iter)
        if (kt < 15) {
            const int nb = 1 - cur;
            *(ushort4*)(wp0 + nb * bufStride) = cvt4(n0);
            *(ushort4*)(wp1 + nb * bufStride) = cvt4(n1);
        }
        __syncthreads();
    }

    // Epilogue: tanh + v-dot, reduce over N. C layout: col=lane&15, row=lk*4+r
    float phv[8], vv[8];
    #pragma unroll
    for (int nj = 0; nj < 8; ++nj) {
        const int n = wn + nj * 16 + ln15;
        phv[nj] = proj_h[bb * HID + n];
        vv[nj]  = v[n];
    }

    #pragma unroll
    for (int mi = 0; mi < 4; ++mi) {
        #pragma unroll
        for (int r = 0; r < 4; ++r) {
            float s = 0.f;
            #pragma unroll
            for (int nj = 0; nj < 8; ++nj) {
                float x = acc[mi][nj][r] + phv[nj];
                float e = __expf(2.f * x);
                float th = 1.f - 2.f / (e + 1.f);  // tanh, saturation-safe
                s += vv[nj] * th;
            }
            s += __shfl_xor(s, 8, 64);
            s += __shfl_xor(s, 4, 64);
            s += __shfl_xor(s, 2, 64);
            s += __shfl_xor(s, 1, 64);
            if (ln15 == 0)
                sred[wnG][wm + mi * 16 + lk * 4 + r] = s;
        }
    }
    __syncthreads();
    if (t < 128)
        scores[m0 + t] = sred[0][t] + sred[1][t] + sred[2][t] + sred[3][t];
}

// ---------------------------------------------------------------------------
// Kernel 3: softmax + context. 2 blocks per batch (512 blocks, 2/CU),
// each block owns 256 columns; softmax computed redundantly per block.
// ---------------------------------------------------------------------------
__global__ __launch_bounds__(1024) void softmax_ctx(
    const float* __restrict__ scores,  // [256][1024]
    const float* __restrict__ enc,     // [256][1024][512]
    float* __restrict__ ctx_out,       // [256][512]
    float* __restrict__ alpha_out)     // [256][1024]
{
    __shared__ float salpha[SEQ];
    __shared__ float sctx[16][256];
    __shared__ float sbufA[16], sbufB[16];
    const int b    = blockIdx.x >> 1;
    const int half = blockIdx.x & 1;
    const int t = threadIdx.x;
    const int w = t >> 6;

    float sc = scores[(size_t)b * SEQ + t];

    float mx = sc;
    #pragma unroll
    for (int m = 32; m >= 1; m >>= 1) mx = fmaxf(mx, __shfl_xor(mx, m, 64));
    if ((t & 63) == 0) sbufA[w] = mx;
    __syncthreads();
    float gm = sbufA[0];
    #pragma unroll
    for (int i = 1; i < 16; ++i) gm = fmaxf(gm, sbufA[i]);

    float e0 = __expf(sc - gm);
    float ssum = e0;
    #pragma unroll
    for (int m = 32; m >= 1; m >>= 1) ssum += __shfl_xor(ssum, m, 64);
    if ((t & 63) == 0) sbufB[w] = ssum;
    __syncthreads();
    float tot = 0.f;
    #pragma unroll
    for (int i = 0; i < 16; ++i) tot += sbufB[i];
    const float inv = 1.f / tot;

    const float a0 = e0 * inv;
    salpha[t] = a0;
    if (half == 0) alpha_out[(size_t)b * SEQ + t] = a0;
    __syncthreads();

    // context: tx owns 4 cols at half*256 + tx*4; ty strides rows by 16
    const int tx = t & 63;
    const int ty = t >> 6;
    float4 acc = make_float4(0.f, 0.f, 0.f, 0.f);
    const float* ep = enc + (size_t)b * SEQ * ENCD + half * 256 + (size_t)tx * 4;
    #pragma unroll 8
    for (int l = ty; l < SEQ; l += 16) {
        float4 vv = *(const float4*)(ep + (size_t)l * ENCD);
        float a = salpha[l];
        acc.x += a * vv.x; acc.y += a * vv.y;
        acc.z += a * vv.z; acc.w += a * vv.w;
    }
    *(float4*)(&sctx[ty][tx * 4]) = acc;
    __syncthreads();

    if (t < 256) {
        float s = 0.f;
        #pragma unroll
        for (int y = 0; y < 16; ++y) s += sctx[y][t];
        ctx_out[(size_t)b * ENCD + half * 256 + t] = s;
    }
}

// ---------------------------------------------------------------------------
extern "C" void kernel_launch(void* const* d_in, const int* in_sizes, int n_in,
                              void* d_out, int out_size, void* d_ws, size_t ws_size,
                              hipStream_t stream) {
    const float* dh  = (const float*)d_in[0];  // decoder_hidden [256][512]
    const float* enc = (const float*)d_in[1];  // encoder_outputs [256][1024][512]
    const float* W_h = (const float*)d_in[2];  // [512][512]
    const float* W_s = (const float*)d_in[3];  // [512][512]
    const float* v   = (const float*)d_in[4];  // [1][512]

    float* ws = (float*)d_ws;
    float* proj_h = ws;                                 // 131072 floats
    float* scores = ws + 131072;                        // 262144 floats
    unsigned short* Bshuf = (unsigned short*)(ws + 131072 + 262144); // 262144 bf16

    float* ctx   = (float*)d_out;              // [256][512]
    float* alpha = (float*)d_out + NB * HID;   // [256][1024]

    prep_kernel<<<128, 256, 0, stream>>>(dh, W_h, W_s, proj_h, Bshuf);
    score_gemm<<<M_TOTAL / 128, 512, 0, stream>>>(enc, Bshuf, proj_h, v, scores);
    softmax_ctx<<<NB * 2, 1024, 0, stream>>>(scores, enc, ctx, alpha);
}